// Round 2
// baseline (1116.816 us; speedup 1.0000x reference)
//
#include <hip/hip_runtime.h>
#include <stdint.h>

typedef unsigned long long u64;

#define B_ROWS 8192
#define K_BITS 4096
#define KW 64      // u64 words along K (4096/64)
#define KC 16      // u64 words per K-chunk staged in LDS
#define KSTRIDE 18 // LDS row stride in u64 (144 B: 16B-aligned, bank-spread)
#define BM 128
#define BN 128

// ---------------- init ----------------
__global__ void init_stats(int* sum0, u64* sq0, int* sum1, u64* sq1,
                           int* sum2, u64* sq2, int* smax, int* smin, float* esum) {
  int i = blockIdx.x * 256 + threadIdx.x;
  if (i < 4096) { sum0[i] = 0; sq0[i] = 0; sum1[i] = 0; sq1[i] = 0; }
  if (i < 1024) {
    sum2[i] = 0; sq2[i] = 0;
    smax[i] = (int)0x80000000; smin[i] = 0x7fffffff;
    esum[i] = 0.0f;
  }
}

// ---------------- binarize + bit-pack x ----------------
__global__ void pack_x(const float* __restrict__ x, u64* __restrict__ bits) {
  int idx = blockIdx.x * 256 + threadIdx.x;
  float v = x[idx];
  u64 m = __ballot(v >= 0.5f);
  if ((threadIdx.x & 63) == 0) bits[idx >> 6] = m;
}

// ---------------- binarize + transpose-pack W (K x N  ->  [N][KW] bits) --------
__global__ void pack_w(const float* __restrict__ W, u64* __restrict__ Wb,
                       int N, int nlog2) {
  int t = blockIdx.x * 256 + threadIdx.x;   // N*64 threads
  int n = t & (N - 1);
  int w = t >> nlog2;
  const float* p = W + (size_t)(w * 64) * N + n;
  u64 m = 0;
  #pragma unroll 8
  for (int b = 0; b < 64; b++)
    m |= (u64)(p[(size_t)b * N] >= 0.0f) << b;
  Wb[(size_t)n * KW + w] = m;
}

// ---------------- XNOR-popcount GEMM + fused column stats ----------------
// S[r][n] = 4096 - 2*popc(Ab[r] ^ Wb[n]); fused per-column sum / sum-sq / minmax.
__global__ __launch_bounds__(256, 4)
void gemm_xnor(const u64* __restrict__ Ab, const u64* __restrict__ Wb,
               short* __restrict__ S, int N,
               int* __restrict__ colsum, u64* __restrict__ colsq,
               int* __restrict__ colmax, int* __restrict__ colmin, int dominmax) {
  __shared__ u64 As[BM][KSTRIDE];   // only [.][0..KC) used; 18 KiB
  __shared__ u64 Bs[BN][KSTRIDE];

  const int tid = threadIdx.x;
  const int tx = tid & 15, ty = tid >> 4;
  const int row0 = blockIdx.y * BM, col0 = blockIdx.x * BN;

  int acc[8][8];
  #pragma unroll
  for (int i = 0; i < 8; i++)
    #pragma unroll
    for (int j = 0; j < 8; j++) acc[i][j] = 0;

  for (int k0 = 0; k0 < KW; k0 += KC) {
    #pragma unroll
    for (int i = 0; i < 4; i++) {
      int idx = tid + i * 256;          // 0..1023
      int r = idx >> 3, wp = (idx & 7) << 1;
      *(ulonglong2*)&As[r][wp] = *(const ulonglong2*)&Ab[(size_t)(row0 + r) * KW + k0 + wp];
      *(ulonglong2*)&Bs[r][wp] = *(const ulonglong2*)&Wb[(size_t)(col0 + r) * KW + k0 + wp];
    }
    __syncthreads();
    #pragma unroll 1
    for (int w = 0; w < KC; w++) {
      u64 a[8], b[8];
      #pragma unroll
      for (int i = 0; i < 8; i++) a[i] = As[ty + 16 * i][w];
      #pragma unroll
      for (int j = 0; j < 8; j++) b[j] = Bs[tx + 16 * j][w];
      #pragma unroll
      for (int j = 0; j < 8; j++) {
        #pragma unroll
        for (int i = 0; i < 8; i++) {
          u64 x = a[i] ^ b[j];
          // add(ctpop32, acc) folds into v_bcnt_u32_b32 accumulate operand
          acc[i][j] = __builtin_popcount((unsigned)x) + acc[i][j];
          acc[i][j] = __builtin_popcount((unsigned)(x >> 32)) + acc[i][j];
        }
      }
    }
    __syncthreads();
  }

  // epilogue: write s (int16) + per-thread column partials
  int ps[8], pq[8], mx[8], mn[8];
  #pragma unroll
  for (int j = 0; j < 8; j++) { ps[j] = 0; pq[j] = 0; mx[j] = -100000; mn[j] = 100000; }
  #pragma unroll
  for (int i = 0; i < 8; i++) {
    size_t rowoff = (size_t)(row0 + ty + 16 * i) * N + col0;
    #pragma unroll
    for (int j = 0; j < 8; j++) {
      int s = K_BITS - 2 * acc[i][j];
      S[rowoff + tx + 16 * j] = (short)s;
      ps[j] += s;
      pq[j] += s * s;                       // <= 8*4096^2 = 2^27, fits int32
      mx[j] = (s > mx[j]) ? s : mx[j];
      mn[j] = (s < mn[j]) ? s : mn[j];
    }
  }
  // reuse As/Bs LDS for reductions (compute phase fully barriered above)
  int (*redA)[BN] = (int(*)[BN])As;
  int (*redB)[BN] = (int(*)[BN])Bs;
  #pragma unroll
  for (int j = 0; j < 8; j++) { redA[ty][tx + 16 * j] = ps[j]; redB[ty][tx + 16 * j] = pq[j]; }
  __syncthreads();
  if (tid < BN) {
    int ssum = 0; long long sq = 0;
    #pragma unroll
    for (int t = 0; t < 16; t++) { ssum += redA[t][tid]; sq += (long long)redB[t][tid]; }
    atomicAdd(&colsum[col0 + tid], ssum);
    atomicAdd(&colsq[col0 + tid], (u64)sq);
  }
  if (dominmax) {
    __syncthreads();
    #pragma unroll
    for (int j = 0; j < 8; j++) { redA[ty][tx + 16 * j] = mx[j]; redB[ty][tx + 16 * j] = mn[j]; }
    __syncthreads();
    if (tid < BN) {
      int m1 = -100000, m2 = 100000;
      #pragma unroll
      for (int t = 0; t < 16; t++) {
        m1 = (redA[t][tid] > m1) ? redA[t][tid] : m1;
        m2 = (redB[t][tid] < m2) ? redB[t][tid] : m2;
      }
      atomicMax(&colmax[col0 + tid], m1);
      atomicMin(&colmin[col0 + tid], m2);
    }
  }
}

// ---------------- per-column scale c = gamma / sqrt(var + eps) ----------------
__global__ void stats01(const int* __restrict__ colsum, const u64* __restrict__ colsq,
                        const float* __restrict__ gamma, int layer, float* __restrict__ c) {
  int n = blockIdx.x * 256 + threadIdx.x;
  double mu  = (double)colsum[n] / 8192.0;
  double var = (double)colsq[n] / 8192.0 - mu * mu;
  c[n] = (float)((double)gamma[layer] / sqrt(var + 1e-5));
}

// ---------------- binarize BN output -> next-layer bits ----------------
// a >= 0  <=>  (8192*s - sum)*c/8192 + beta >= 0 ; t is an exact integer.
// each thread: 2 elements at idx0 = wave_base + lane and idx0 + 64 -> 2 ballots,
// lane 0 writes two consecutive u64 words directly (no bit interleaving needed).
__global__ void binarize_pack(const short* __restrict__ S, const int* __restrict__ colsum,
                              const float* __restrict__ c, const float* __restrict__ beta,
                              int layer, u64* __restrict__ bits) {
  int gwave = (blockIdx.x * 256 + threadIdx.x) >> 6;
  int lane = threadIdx.x & 63;
  int idx0 = (gwave << 7) + lane;
  int idx1 = idx0 + 64;
  int n0 = idx0 & (K_BITS - 1);
  int n1 = idx1 & (K_BITS - 1);
  float bv = beta[layer];
  int t0 = (int)S[idx0] * 8192 - colsum[n0];
  int t1 = (int)S[idx1] * 8192 - colsum[n1];
  float a0 = (float)t0 * c[n0] * (1.0f / 8192.0f) + bv;
  float a1 = (float)t1 * c[n1] * (1.0f / 8192.0f) + bv;
  u64 m0 = __ballot(a0 >= 0.0f);
  u64 m1 = __ballot(a1 >= 0.0f);
  if (lane == 0) {
    bits[(gwave << 1) + 0] = m0;
    bits[(gwave << 1) + 1] = m1;
  }
}

// ---------------- last-layer stats: scale + reference s for softmax ------------
__global__ void final_stats(const int* __restrict__ colsum, const u64* __restrict__ colsq,
                            const int* __restrict__ colmax, const int* __restrict__ colmin,
                            const float* __restrict__ gamma,
                            float* __restrict__ c, int* __restrict__ sref) {
  int n = blockIdx.x * 256 + threadIdx.x;  // 1024
  double mu  = (double)colsum[n] / 8192.0;
  double var = (double)colsq[n] / 8192.0 - mu * mu;
  float cv = (float)((double)gamma[2] / sqrt(var + 1e-5));
  c[n] = cv;
  sref[n] = (cv >= 0.0f) ? colmax[n] : colmin[n];   // argmax of a per column
}

// ---------------- softmax over batch dim (axis 0), per column ----------------
__global__ void softmax_p1(const short* __restrict__ S2, const int* __restrict__ sref,
                           const float* __restrict__ c, float* __restrict__ out,
                           float* __restrict__ esum) {
  int n  = blockIdx.x * 256 + threadIdx.x;   // gridDim.x = 4 -> n in [0,1024)
  int r0 = blockIdx.y * 128;
  float cs = c[n]; int sr = sref[n];
  float acc = 0.0f;
  for (int r = 0; r < 128; r++) {
    size_t idx = (size_t)(r0 + r) * 1024 + n;
    float e = __expf((float)((int)S2[idx] - sr) * cs);   // (a - amax), always <= 0
    out[idx] = e;
    acc += e;
  }
  atomicAdd(&esum[n], acc);
}

__global__ void softmax_p2(float* __restrict__ out, const float* __restrict__ esum) {
  int idx = blockIdx.x * 256 + threadIdx.x;
  out[idx] /= esum[idx & 1023];
}

// ---------------- launcher ----------------
extern "C" void kernel_launch(void* const* d_in, const int* in_sizes, int n_in,
                              void* d_out, int out_size, void* d_ws, size_t ws_size,
                              hipStream_t stream) {
  const float* x     = (const float*)d_in[0];
  const float* W0    = (const float*)d_in[1];
  const float* W1    = (const float*)d_in[2];
  const float* W2    = (const float*)d_in[3];
  const float* gamma = (const float*)d_in[4];
  const float* beta  = (const float*)d_in[5];
  float* out = (float*)d_out;

  char* ws = (char*)d_ws;
  u64*   bitsA = (u64*)(ws + 0);                  // 4 MiB  (8192 x 64 u64)
  u64*   bitsB = (u64*)(ws + (4ull  << 20));      // 4 MiB
  u64*   Wb0   = (u64*)(ws + (8ull  << 20));      // 2 MiB  (4096 x 64 u64)
  u64*   Wb1   = (u64*)(ws + (10ull << 20));      // 2 MiB
  u64*   Wb2   = (u64*)(ws + (12ull << 20));      // 0.5 MiB (1024 x 64 u64)
  short* S     = (short*)(ws + (16ull << 20));    // 64 MiB (8192 x 4096 int16)
  char*  st    = ws + (80ull << 20);
  int*   sum0 = (int*)(st);                        // 16 KB
  u64*   sq0  = (u64*)(st + 16 * 1024);            // 32 KB
  int*   sum1 = (int*)(st + 48 * 1024);            // 16 KB
  u64*   sq1  = (u64*)(st + 64 * 1024);            // 32 KB
  int*   sum2 = (int*)(st + 96 * 1024);            // 4 KB
  u64*   sq2  = (u64*)(st + 100 * 1024);           // 8 KB
  int*   smax = (int*)(st + 108 * 1024);           // 4 KB
  int*   smin = (int*)(st + 112 * 1024);           // 4 KB
  float* c0   = (float*)(st + 116 * 1024);         // 16 KB
  float* c1   = (float*)(st + 132 * 1024);         // 16 KB
  float* c2   = (float*)(st + 148 * 1024);         // 4 KB
  int*   sref = (int*)(st + 152 * 1024);           // 4 KB
  float* esum = (float*)(st + 156 * 1024);         // 4 KB

  init_stats<<<16, 256, 0, stream>>>(sum0, sq0, sum1, sq1, sum2, sq2, smax, smin, esum);
  pack_x<<<(B_ROWS * K_BITS) / 256, 256, 0, stream>>>(x, bitsA);
  pack_w<<<(4096 * 64) / 256, 256, 0, stream>>>(W0, Wb0, 4096, 12);
  pack_w<<<(4096 * 64) / 256, 256, 0, stream>>>(W1, Wb1, 4096, 12);
  pack_w<<<(1024 * 64) / 256, 256, 0, stream>>>(W2, Wb2, 1024, 10);

  // layer 0
  gemm_xnor<<<dim3(32, 64), 256, 0, stream>>>(bitsA, Wb0, S, 4096, sum0, sq0, nullptr, nullptr, 0);
  stats01<<<16, 256, 0, stream>>>(sum0, sq0, gamma, 0, c0);
  binarize_pack<<<(B_ROWS * 4096) / 512, 256, 0, stream>>>(S, sum0, c0, beta, 0, bitsB);

  // layer 1
  gemm_xnor<<<dim3(32, 64), 256, 0, stream>>>(bitsB, Wb1, S, 4096, sum1, sq1, nullptr, nullptr, 0);
  stats01<<<16, 256, 0, stream>>>(sum1, sq1, gamma, 1, c1);
  binarize_pack<<<(B_ROWS * 4096) / 512, 256, 0, stream>>>(S, sum1, c1, beta, 1, bitsA);

  // layer 2 (N=1024) + batch-dim softmax
  gemm_xnor<<<dim3(8, 64), 256, 0, stream>>>(bitsA, Wb2, S, 1024, sum2, sq2, smax, smin, 1);
  final_stats<<<4, 256, 0, stream>>>(sum2, sq2, smax, smin, gamma, c2, sref);
  softmax_p1<<<dim3(4, 64), 256, 0, stream>>>(S, sref, c2, out, esum);
  softmax_p2<<<(B_ROWS * 1024) / 256, 256, 0, stream>>>(out, esum);
}

// Round 3
// 1107.393 us; speedup vs baseline: 1.0085x; 1.0085x over previous
//
#include <hip/hip_runtime.h>
#include <stdint.h>

typedef unsigned long long u64;

#define B_ROWS 8192
#define K_BITS 4096
#define KW 64      // u64 words along K (4096/64)
#define KC 16      // u64 words per K-chunk staged in LDS
#define KSTRIDE 18 // LDS row stride in u64 (144 B: 16B-aligned at even w, bank-spread)
#define BM 128
#define BN 128

// ---------------- init ----------------
__global__ void init_stats(int* sum0, u64* sq0, int* sum1, u64* sq1,
                           int* sum2, u64* sq2, int* smax, int* smin, float* esum) {
  int i = blockIdx.x * 256 + threadIdx.x;
  if (i < 4096) { sum0[i] = 0; sq0[i] = 0; sum1[i] = 0; sq1[i] = 0; }
  if (i < 1024) {
    sum2[i] = 0; sq2[i] = 0;
    smax[i] = (int)0x80000000; smin[i] = 0x7fffffff;
    esum[i] = 0.0f;
  }
}

// ---------------- binarize + bit-pack x ----------------
__global__ void pack_x(const float* __restrict__ x, u64* __restrict__ bits) {
  int idx = blockIdx.x * 256 + threadIdx.x;
  float v = x[idx];
  u64 m = __ballot(v >= 0.5f);
  if ((threadIdx.x & 63) == 0) bits[idx >> 6] = m;
}

// ---------------- binarize + transpose-pack W (K x N  ->  [N][KW] bits) --------
__global__ void pack_w(const float* __restrict__ W, u64* __restrict__ Wb,
                       int N, int nlog2) {
  int t = blockIdx.x * 256 + threadIdx.x;   // N*64 threads
  int n = t & (N - 1);
  int w = t >> nlog2;
  const float* p = W + (size_t)(w * 64) * N + n;
  u64 m = 0;
  #pragma unroll 8
  for (int b = 0; b < 64; b++)
    m |= (u64)(p[(size_t)b * N] >= 0.0f) << b;
  Wb[(size_t)n * KW + w] = m;
}

// ---------------- XNOR-popcount GEMM + fused column stats ----------------
// S[r][n] = 4096 - 2*popc(Ab[r] ^ Wb[n]); fused per-column sum / sum-sq / minmax.
// launch_bounds(256,2): 256 regs/wave so 64 accs + 64 operand VGPRs stay in
// arch VGPRs (at (256,4) the allocator split 64 VGPR/64 AGPR and every popcount
// paid v_accvgpr_read/write round-trips -> 2.7x inst bloat, round-2 evidence).
__global__ __launch_bounds__(256, 2)
void gemm_xnor(const u64* __restrict__ Ab, const u64* __restrict__ Wb,
               short* __restrict__ S, int N,
               int* __restrict__ colsum, u64* __restrict__ colsq,
               int* __restrict__ colmax, int* __restrict__ colmin, int dominmax) {
  __shared__ u64 As[BM][KSTRIDE];   // only [.][0..KC) used; 18 KiB
  __shared__ u64 Bs[BN][KSTRIDE];

  const int tid = threadIdx.x;
  const int tx = tid & 15, ty = tid >> 4;
  const int row0 = blockIdx.y * BM, col0 = blockIdx.x * BN;

  int acc[8][8];
  #pragma unroll
  for (int i = 0; i < 8; i++)
    #pragma unroll
    for (int j = 0; j < 8; j++) acc[i][j] = 0;

  for (int k0 = 0; k0 < KW; k0 += KC) {
    #pragma unroll
    for (int i = 0; i < 4; i++) {
      int idx = tid + i * 256;          // 0..1023
      int r = idx >> 3, wp = (idx & 7) << 1;
      *(ulonglong2*)&As[r][wp] = *(const ulonglong2*)&Ab[(size_t)(row0 + r) * KW + k0 + wp];
      *(ulonglong2*)&Bs[r][wp] = *(const ulonglong2*)&Wb[(size_t)(col0 + r) * KW + k0 + wp];
    }
    __syncthreads();
    #pragma unroll 1
    for (int w = 0; w < KC; w += 2) {
      ulonglong2 a[8], b[8];          // ds_read_b128: 16 LDS insts per 512 VALU
      #pragma unroll
      for (int i = 0; i < 8; i++) a[i] = *(const ulonglong2*)&As[ty + 16 * i][w];
      #pragma unroll
      for (int j = 0; j < 8; j++) b[j] = *(const ulonglong2*)&Bs[tx + 16 * j][w];
      #pragma unroll
      for (int j = 0; j < 8; j++) {
        #pragma unroll
        for (int i = 0; i < 8; i++) {
          u64 x0 = a[i].x ^ b[j].x;
          u64 x1 = a[i].y ^ b[j].y;
          // add(ctpop32, acc) folds into v_bcnt_u32_b32 accumulate operand
          acc[i][j] = __builtin_popcount((unsigned)x0) + acc[i][j];
          acc[i][j] = __builtin_popcount((unsigned)(x0 >> 32)) + acc[i][j];
          acc[i][j] = __builtin_popcount((unsigned)x1) + acc[i][j];
          acc[i][j] = __builtin_popcount((unsigned)(x1 >> 32)) + acc[i][j];
        }
      }
    }
    __syncthreads();
  }

  // epilogue: write s (int16) + per-thread column partials
  int ps[8], pq[8], mx[8], mn[8];
  #pragma unroll
  for (int j = 0; j < 8; j++) { ps[j] = 0; pq[j] = 0; mx[j] = -100000; mn[j] = 100000; }
  #pragma unroll
  for (int i = 0; i < 8; i++) {
    size_t rowoff = (size_t)(row0 + ty + 16 * i) * N + col0;
    #pragma unroll
    for (int j = 0; j < 8; j++) {
      int s = K_BITS - 2 * acc[i][j];
      S[rowoff + tx + 16 * j] = (short)s;
      ps[j] += s;
      pq[j] += s * s;                       // <= 8*4096^2 = 2^27, fits int32
      mx[j] = (s > mx[j]) ? s : mx[j];
      mn[j] = (s < mn[j]) ? s : mn[j];
    }
  }
  // reuse As/Bs LDS for reductions (compute phase fully barriered above)
  int (*redA)[BN] = (int(*)[BN])As;
  int (*redB)[BN] = (int(*)[BN])Bs;
  #pragma unroll
  for (int j = 0; j < 8; j++) { redA[ty][tx + 16 * j] = ps[j]; redB[ty][tx + 16 * j] = pq[j]; }
  __syncthreads();
  if (tid < BN) {
    int ssum = 0; long long sq = 0;
    #pragma unroll
    for (int t = 0; t < 16; t++) { ssum += redA[t][tid]; sq += (long long)redB[t][tid]; }
    atomicAdd(&colsum[col0 + tid], ssum);
    atomicAdd(&colsq[col0 + tid], (u64)sq);
  }
  if (dominmax) {
    __syncthreads();
    #pragma unroll
    for (int j = 0; j < 8; j++) { redA[ty][tx + 16 * j] = mx[j]; redB[ty][tx + 16 * j] = mn[j]; }
    __syncthreads();
    if (tid < BN) {
      int m1 = -100000, m2 = 100000;
      #pragma unroll
      for (int t = 0; t < 16; t++) {
        m1 = (redA[t][tid] > m1) ? redA[t][tid] : m1;
        m2 = (redB[t][tid] < m2) ? redB[t][tid] : m2;
      }
      atomicMax(&colmax[col0 + tid], m1);
      atomicMin(&colmin[col0 + tid], m2);
    }
  }
}

// ---------------- per-column scale c = gamma / sqrt(var + eps) ----------------
__global__ void stats01(const int* __restrict__ colsum, const u64* __restrict__ colsq,
                        const float* __restrict__ gamma, int layer, float* __restrict__ c) {
  int n = blockIdx.x * 256 + threadIdx.x;
  double mu  = (double)colsum[n] / 8192.0;
  double var = (double)colsq[n] / 8192.0 - mu * mu;
  c[n] = (float)((double)gamma[layer] / sqrt(var + 1e-5));
}

// ---------------- binarize BN output -> next-layer bits ----------------
// a >= 0  <=>  (8192*s - sum)*c/8192 + beta >= 0 ; t is an exact integer.
__global__ void binarize_pack(const short* __restrict__ S, const int* __restrict__ colsum,
                              const float* __restrict__ c, const float* __restrict__ beta,
                              int layer, u64* __restrict__ bits) {
  int gwave = (blockIdx.x * 256 + threadIdx.x) >> 6;
  int lane = threadIdx.x & 63;
  int idx0 = (gwave << 7) + lane;
  int idx1 = idx0 + 64;
  int n0 = idx0 & (K_BITS - 1);
  int n1 = idx1 & (K_BITS - 1);
  float bv = beta[layer];
  int t0 = (int)S[idx0] * 8192 - colsum[n0];
  int t1 = (int)S[idx1] * 8192 - colsum[n1];
  float a0 = (float)t0 * c[n0] * (1.0f / 8192.0f) + bv;
  float a1 = (float)t1 * c[n1] * (1.0f / 8192.0f) + bv;
  u64 m0 = __ballot(a0 >= 0.0f);
  u64 m1 = __ballot(a1 >= 0.0f);
  if (lane == 0) {
    bits[(gwave << 1) + 0] = m0;
    bits[(gwave << 1) + 1] = m1;
  }
}

// ---------------- last-layer stats: scale + reference s for softmax ------------
__global__ void final_stats(const int* __restrict__ colsum, const u64* __restrict__ colsq,
                            const int* __restrict__ colmax, const int* __restrict__ colmin,
                            const float* __restrict__ gamma,
                            float* __restrict__ c, int* __restrict__ sref) {
  int n = blockIdx.x * 256 + threadIdx.x;  // 1024
  double mu  = (double)colsum[n] / 8192.0;
  double var = (double)colsq[n] / 8192.0 - mu * mu;
  float cv = (float)((double)gamma[2] / sqrt(var + 1e-5));
  c[n] = cv;
  sref[n] = (cv >= 0.0f) ? colmax[n] : colmin[n];   // argmax of a per column
}

// ---------------- softmax over batch dim (axis 0), per column ----------------
__global__ void softmax_p1(const short* __restrict__ S2, const int* __restrict__ sref,
                           const float* __restrict__ c, float* __restrict__ out,
                           float* __restrict__ esum) {
  int n  = blockIdx.x * 256 + threadIdx.x;   // gridDim.x = 4 -> n in [0,1024)
  int r0 = blockIdx.y * 128;
  float cs = c[n]; int sr = sref[n];
  float acc = 0.0f;
  for (int r = 0; r < 128; r++) {
    size_t idx = (size_t)(r0 + r) * 1024 + n;
    float e = __expf((float)((int)S2[idx] - sr) * cs);   // (a - amax), always <= 0
    out[idx] = e;
    acc += e;
  }
  atomicAdd(&esum[n], acc);
}

__global__ void softmax_p2(float* __restrict__ out, const float* __restrict__ esum) {
  int idx = blockIdx.x * 256 + threadIdx.x;
  out[idx] /= esum[idx & 1023];
}

// ---------------- launcher ----------------
extern "C" void kernel_launch(void* const* d_in, const int* in_sizes, int n_in,
                              void* d_out, int out_size, void* d_ws, size_t ws_size,
                              hipStream_t stream) {
  const float* x     = (const float*)d_in[0];
  const float* W0    = (const float*)d_in[1];
  const float* W1    = (const float*)d_in[2];
  const float* W2    = (const float*)d_in[3];
  const float* gamma = (const float*)d_in[4];
  const float* beta  = (const float*)d_in[5];
  float* out = (float*)d_out;

  char* ws = (char*)d_ws;
  u64*   bitsA = (u64*)(ws + 0);                  // 4 MiB  (8192 x 64 u64)
  u64*   bitsB = (u64*)(ws + (4ull  << 20));      // 4 MiB
  u64*   Wb0   = (u64*)(ws + (8ull  << 20));      // 2 MiB  (4096 x 64 u64)
  u64*   Wb1   = (u64*)(ws + (10ull << 20));      // 2 MiB
  u64*   Wb2   = (u64*)(ws + (12ull << 20));      // 0.5 MiB (1024 x 64 u64)
  short* S     = (short*)(ws + (16ull << 20));    // 64 MiB (8192 x 4096 int16)
  char*  st    = ws + (80ull << 20);
  int*   sum0 = (int*)(st);                        // 16 KB
  u64*   sq0  = (u64*)(st + 16 * 1024);            // 32 KB
  int*   sum1 = (int*)(st + 48 * 1024);            // 16 KB
  u64*   sq1  = (u64*)(st + 64 * 1024);            // 32 KB
  int*   sum2 = (int*)(st + 96 * 1024);            // 4 KB
  u64*   sq2  = (u64*)(st + 100 * 1024);           // 8 KB
  int*   smax = (int*)(st + 108 * 1024);           // 4 KB
  int*   smin = (int*)(st + 112 * 1024);           // 4 KB
  float* c0   = (float*)(st + 116 * 1024);         // 16 KB
  float* c1   = (float*)(st + 132 * 1024);         // 16 KB
  float* c2   = (float*)(st + 148 * 1024);         // 4 KB
  int*   sref = (int*)(st + 152 * 1024);           // 4 KB
  float* esum = (float*)(st + 156 * 1024);         // 4 KB

  init_stats<<<16, 256, 0, stream>>>(sum0, sq0, sum1, sq1, sum2, sq2, smax, smin, esum);
  pack_x<<<(B_ROWS * K_BITS) / 256, 256, 0, stream>>>(x, bitsA);
  pack_w<<<(4096 * 64) / 256, 256, 0, stream>>>(W0, Wb0, 4096, 12);
  pack_w<<<(4096 * 64) / 256, 256, 0, stream>>>(W1, Wb1, 4096, 12);
  pack_w<<<(1024 * 64) / 256, 256, 0, stream>>>(W2, Wb2, 1024, 10);

  // layer 0
  gemm_xnor<<<dim3(32, 64), 256, 0, stream>>>(bitsA, Wb0, S, 4096, sum0, sq0, nullptr, nullptr, 0);
  stats01<<<16, 256, 0, stream>>>(sum0, sq0, gamma, 0, c0);
  binarize_pack<<<(B_ROWS * 4096) / 512, 256, 0, stream>>>(S, sum0, c0, beta, 0, bitsB);

  // layer 1
  gemm_xnor<<<dim3(32, 64), 256, 0, stream>>>(bitsB, Wb1, S, 4096, sum1, sq1, nullptr, nullptr, 0);
  stats01<<<16, 256, 0, stream>>>(sum1, sq1, gamma, 1, c1);
  binarize_pack<<<(B_ROWS * 4096) / 512, 256, 0, stream>>>(S, sum1, c1, beta, 1, bitsA);

  // layer 2 (N=1024) + batch-dim softmax
  gemm_xnor<<<dim3(8, 64), 256, 0, stream>>>(bitsA, Wb2, S, 1024, sum2, sq2, smax, smin, 1);
  final_stats<<<4, 256, 0, stream>>>(sum2, sq2, smax, smin, gamma, c2, sref);
  softmax_p1<<<dim3(4, 64), 256, 0, stream>>>(S, sref, c2, out, esum);
  softmax_p2<<<(B_ROWS * 1024) / 256, 256, 0, stream>>>(out, esum);
}

// Round 4
// 913.985 us; speedup vs baseline: 1.2219x; 1.2116x over previous
//
#include <hip/hip_runtime.h>
#include <stdint.h>

typedef unsigned long long u64;

#define B_ROWS 8192
#define K_BITS 4096
#define KW 64      // u64 words along K (4096/64)
#define KC 16      // u64 words per K-chunk staged in LDS
#define KSTRIDE 18 // LDS row stride in u64 (144 B: 16B-aligned at even w, bank-spread)
#define BM 128
#define BN 128

// ---------------- init ----------------
__global__ void init_stats(int* sum0, u64* sq0, int* sum1, u64* sq1,
                           int* sum2, u64* sq2, int* smax, int* smin, float* esum) {
  int i = blockIdx.x * 256 + threadIdx.x;
  if (i < 4096) { sum0[i] = 0; sq0[i] = 0; sum1[i] = 0; sq1[i] = 0; }
  if (i < 1024) {
    sum2[i] = 0; sq2[i] = 0;
    smax[i] = (int)0x80000000; smin[i] = 0x7fffffff;
    esum[i] = 0.0f;
  }
}

// ---------------- binarize + bit-pack x ----------------
__global__ void pack_x(const float* __restrict__ x, u64* __restrict__ bits) {
  int idx = blockIdx.x * 256 + threadIdx.x;
  float v = x[idx];
  u64 m = __ballot(v >= 0.5f);
  if ((threadIdx.x & 63) == 0) bits[idx >> 6] = m;
}

// ---------------- binarize + transpose-pack W (K x N  ->  [N][KW] bits) --------
__global__ void pack_w(const float* __restrict__ W, u64* __restrict__ Wb,
                       int N, int nlog2) {
  int t = blockIdx.x * 256 + threadIdx.x;   // N*64 threads
  int n = t & (N - 1);
  int w = t >> nlog2;
  const float* p = W + (size_t)(w * 64) * N + n;
  u64 m = 0;
  #pragma unroll 8
  for (int b = 0; b < 64; b++)
    m |= (u64)(p[(size_t)b * N] >= 0.0f) << b;
  Wb[(size_t)n * KW + w] = m;
}

// xor + popcount-accumulate, pinned to exactly 2 VALU insts:
//   v_xor_b32 t, a, b ; v_bcnt_u32_b32 acc, t, acc
#define XNOR_STEP(acc, av, bv) do {                                   \
    unsigned _t;                                                      \
    asm("v_xor_b32 %0, %1, %2" : "=v"(_t) : "v"(av), "v"(bv));        \
    asm("v_bcnt_u32_b32 %0, %1, %0" : "+v"(acc) : "v"(_t));           \
  } while (0)

// ---------------- XNOR-popcount GEMM + fused column stats ----------------
// S[r][n] = 4096 - 2*popc(Ab[r] ^ Wb[n]); fused per-column sum / sum-sq / minmax.
// Inner loop is inline-asm pinned: 4x (v_xor_b32 + v_bcnt_u32_b32) per u64 pair,
// accumulators forced into arch VGPRs by the "v" constraints.
__global__ __launch_bounds__(256, 2)
void gemm_xnor(const u64* __restrict__ Ab, const u64* __restrict__ Wb,
               short* __restrict__ S, int N,
               int* __restrict__ colsum, u64* __restrict__ colsq,
               int* __restrict__ colmax, int* __restrict__ colmin, int dominmax) {
  __shared__ alignas(16) u64 As[BM][KSTRIDE];   // only [.][0..KC) used; 18 KiB
  __shared__ alignas(16) u64 Bs[BN][KSTRIDE];

  const int tid = threadIdx.x;
  const int tx = tid & 15, ty = tid >> 4;
  const int row0 = blockIdx.y * BM, col0 = blockIdx.x * BN;

  int acc[8][8];
  #pragma unroll
  for (int i = 0; i < 8; i++)
    #pragma unroll
    for (int j = 0; j < 8; j++) acc[i][j] = 0;

  for (int k0 = 0; k0 < KW; k0 += KC) {
    #pragma unroll
    for (int i = 0; i < 4; i++) {
      int idx = tid + i * 256;          // 0..1023
      int r = idx >> 3, wp = (idx & 7) << 1;
      *(ulonglong2*)&As[r][wp] = *(const ulonglong2*)&Ab[(size_t)(row0 + r) * KW + k0 + wp];
      *(ulonglong2*)&Bs[r][wp] = *(const ulonglong2*)&Wb[(size_t)(col0 + r) * KW + k0 + wp];
    }
    __syncthreads();
    #pragma unroll 1
    for (int w = 0; w < KC; w += 2) {
      uint4 a[8], b[8];               // ds_read_b128: 2 u64 per read
      #pragma unroll
      for (int i = 0; i < 8; i++) a[i] = *(const uint4*)&As[ty + 16 * i][w];
      #pragma unroll
      for (int j = 0; j < 8; j++) b[j] = *(const uint4*)&Bs[tx + 16 * j][w];
      #pragma unroll
      for (int j = 0; j < 8; j++) {
        #pragma unroll
        for (int i = 0; i < 8; i++) {
          XNOR_STEP(acc[i][j], a[i].x, b[j].x);
          XNOR_STEP(acc[i][j], a[i].y, b[j].y);
          XNOR_STEP(acc[i][j], a[i].z, b[j].z);
          XNOR_STEP(acc[i][j], a[i].w, b[j].w);
        }
      }
    }
    __syncthreads();
  }

  // epilogue: write s (int16) + per-thread column partials
  int ps[8], pq[8], mx[8], mn[8];
  #pragma unroll
  for (int j = 0; j < 8; j++) { ps[j] = 0; pq[j] = 0; mx[j] = -100000; mn[j] = 100000; }
  #pragma unroll
  for (int i = 0; i < 8; i++) {
    size_t rowoff = (size_t)(row0 + ty + 16 * i) * N + col0;
    #pragma unroll
    for (int j = 0; j < 8; j++) {
      int s = K_BITS - 2 * acc[i][j];
      S[rowoff + tx + 16 * j] = (short)s;
      ps[j] += s;
      pq[j] += s * s;                       // <= 8*4096^2 = 2^27, fits int32
      mx[j] = (s > mx[j]) ? s : mx[j];
      mn[j] = (s < mn[j]) ? s : mn[j];
    }
  }
  // reuse As/Bs LDS for reductions (compute phase fully barriered above)
  int (*redA)[BN] = (int(*)[BN])As;
  int (*redB)[BN] = (int(*)[BN])Bs;
  #pragma unroll
  for (int j = 0; j < 8; j++) { redA[ty][tx + 16 * j] = ps[j]; redB[ty][tx + 16 * j] = pq[j]; }
  __syncthreads();
  if (tid < BN) {
    int ssum = 0; long long sq = 0;
    #pragma unroll
    for (int t = 0; t < 16; t++) { ssum += redA[t][tid]; sq += (long long)redB[t][tid]; }
    atomicAdd(&colsum[col0 + tid], ssum);
    atomicAdd(&colsq[col0 + tid], (u64)sq);
  }
  if (dominmax) {
    __syncthreads();
    #pragma unroll
    for (int j = 0; j < 8; j++) { redA[ty][tx + 16 * j] = mx[j]; redB[ty][tx + 16 * j] = mn[j]; }
    __syncthreads();
    if (tid < BN) {
      int m1 = -100000, m2 = 100000;
      #pragma unroll
      for (int t = 0; t < 16; t++) {
        m1 = (redA[t][tid] > m1) ? redA[t][tid] : m1;
        m2 = (redB[t][tid] < m2) ? redB[t][tid] : m2;
      }
      atomicMax(&colmax[col0 + tid], m1);
      atomicMin(&colmin[col0 + tid], m2);
    }
  }
}

// ---------------- per-column scale c = gamma / sqrt(var + eps) ----------------
__global__ void stats01(const int* __restrict__ colsum, const u64* __restrict__ colsq,
                        const float* __restrict__ gamma, int layer, float* __restrict__ c) {
  int n = blockIdx.x * 256 + threadIdx.x;
  double mu  = (double)colsum[n] / 8192.0;
  double var = (double)colsq[n] / 8192.0 - mu * mu;
  c[n] = (float)((double)gamma[layer] / sqrt(var + 1e-5));
}

// ---------------- binarize BN output -> next-layer bits ----------------
__global__ void binarize_pack(const short* __restrict__ S, const int* __restrict__ colsum,
                              const float* __restrict__ c, const float* __restrict__ beta,
                              int layer, u64* __restrict__ bits) {
  int gwave = (blockIdx.x * 256 + threadIdx.x) >> 6;
  int lane = threadIdx.x & 63;
  int idx0 = (gwave << 7) + lane;
  int idx1 = idx0 + 64;
  int n0 = idx0 & (K_BITS - 1);
  int n1 = idx1 & (K_BITS - 1);
  float bv = beta[layer];
  int t0 = (int)S[idx0] * 8192 - colsum[n0];
  int t1 = (int)S[idx1] * 8192 - colsum[n1];
  float a0 = (float)t0 * c[n0] * (1.0f / 8192.0f) + bv;
  float a1 = (float)t1 * c[n1] * (1.0f / 8192.0f) + bv;
  u64 m0 = __ballot(a0 >= 0.0f);
  u64 m1 = __ballot(a1 >= 0.0f);
  if (lane == 0) {
    bits[(gwave << 1) + 0] = m0;
    bits[(gwave << 1) + 1] = m1;
  }
}

// ---------------- last-layer stats: scale + reference s for softmax ------------
__global__ void final_stats(const int* __restrict__ colsum, const u64* __restrict__ colsq,
                            const int* __restrict__ colmax, const int* __restrict__ colmin,
                            const float* __restrict__ gamma,
                            float* __restrict__ c, int* __restrict__ sref) {
  int n = blockIdx.x * 256 + threadIdx.x;  // 1024
  double mu  = (double)colsum[n] / 8192.0;
  double var = (double)colsq[n] / 8192.0 - mu * mu;
  float cv = (float)((double)gamma[2] / sqrt(var + 1e-5));
  c[n] = cv;
  sref[n] = (cv >= 0.0f) ? colmax[n] : colmin[n];   // argmax of a per column
}

// ---------------- softmax over batch dim (axis 0), per column ----------------
__global__ void softmax_p1(const short* __restrict__ S2, const int* __restrict__ sref,
                           const float* __restrict__ c, float* __restrict__ out,
                           float* __restrict__ esum) {
  int n  = blockIdx.x * 256 + threadIdx.x;   // gridDim.x = 4 -> n in [0,1024)
  int r0 = blockIdx.y * 128;
  float cs = c[n]; int sr = sref[n];
  float acc = 0.0f;
  for (int r = 0; r < 128; r++) {
    size_t idx = (size_t)(r0 + r) * 1024 + n;
    float e = __expf((float)((int)S2[idx] - sr) * cs);   // (a - amax), always <= 0
    out[idx] = e;
    acc += e;
  }
  atomicAdd(&esum[n], acc);
}

__global__ void softmax_p2(float* __restrict__ out, const float* __restrict__ esum) {
  int idx = blockIdx.x * 256 + threadIdx.x;
  out[idx] /= esum[idx & 1023];
}

// ---------------- launcher ----------------
extern "C" void kernel_launch(void* const* d_in, const int* in_sizes, int n_in,
                              void* d_out, int out_size, void* d_ws, size_t ws_size,
                              hipStream_t stream) {
  const float* x     = (const float*)d_in[0];
  const float* W0    = (const float*)d_in[1];
  const float* W1    = (const float*)d_in[2];
  const float* W2    = (const float*)d_in[3];
  const float* gamma = (const float*)d_in[4];
  const float* beta  = (const float*)d_in[5];
  float* out = (float*)d_out;

  char* ws = (char*)d_ws;
  u64*   bitsA = (u64*)(ws + 0);                  // 4 MiB  (8192 x 64 u64)
  u64*   bitsB = (u64*)(ws + (4ull  << 20));      // 4 MiB
  u64*   Wb0   = (u64*)(ws + (8ull  << 20));      // 2 MiB  (4096 x 64 u64)
  u64*   Wb1   = (u64*)(ws + (10ull << 20));      // 2 MiB
  u64*   Wb2   = (u64*)(ws + (12ull << 20));      // 0.5 MiB (1024 x 64 u64)
  short* S     = (short*)(ws + (16ull << 20));    // 64 MiB (8192 x 4096 int16)
  char*  st    = ws + (80ull << 20);
  int*   sum0 = (int*)(st);                        // 16 KB
  u64*   sq0  = (u64*)(st + 16 * 1024);            // 32 KB
  int*   sum1 = (int*)(st + 48 * 1024);            // 16 KB
  u64*   sq1  = (u64*)(st + 64 * 1024);            // 32 KB
  int*   sum2 = (int*)(st + 96 * 1024);            // 4 KB
  u64*   sq2  = (u64*)(st + 100 * 1024);           // 8 KB
  int*   smax = (int*)(st + 108 * 1024);           // 4 KB
  int*   smin = (int*)(st + 112 * 1024);           // 4 KB
  float* c0   = (float*)(st + 116 * 1024);         // 16 KB
  float* c1   = (float*)(st + 132 * 1024);         // 16 KB
  float* c2   = (float*)(st + 148 * 1024);         // 4 KB
  int*   sref = (int*)(st + 152 * 1024);           // 4 KB
  float* esum = (float*)(st + 156 * 1024);         // 4 KB

  init_stats<<<16, 256, 0, stream>>>(sum0, sq0, sum1, sq1, sum2, sq2, smax, smin, esum);
  pack_x<<<(B_ROWS * K_BITS) / 256, 256, 0, stream>>>(x, bitsA);
  pack_w<<<(4096 * 64) / 256, 256, 0, stream>>>(W0, Wb0, 4096, 12);
  pack_w<<<(4096 * 64) / 256, 256, 0, stream>>>(W1, Wb1, 4096, 12);
  pack_w<<<(1024 * 64) / 256, 256, 0, stream>>>(W2, Wb2, 1024, 10);

  // layer 0
  gemm_xnor<<<dim3(32, 64), 256, 0, stream>>>(bitsA, Wb0, S, 4096, sum0, sq0, nullptr, nullptr, 0);
  stats01<<<16, 256, 0, stream>>>(sum0, sq0, gamma, 0, c0);
  binarize_pack<<<(B_ROWS * 4096) / 512, 256, 0, stream>>>(S, sum0, c0, beta, 0, bitsB);

  // layer 1
  gemm_xnor<<<dim3(32, 64), 256, 0, stream>>>(bitsB, Wb1, S, 4096, sum1, sq1, nullptr, nullptr, 0);
  stats01<<<16, 256, 0, stream>>>(sum1, sq1, gamma, 1, c1);
  binarize_pack<<<(B_ROWS * 4096) / 512, 256, 0, stream>>>(S, sum1, c1, beta, 1, bitsA);

  // layer 2 (N=1024) + batch-dim softmax
  gemm_xnor<<<dim3(8, 64), 256, 0, stream>>>(bitsA, Wb2, S, 1024, sum2, sq2, smax, smin, 1);
  final_stats<<<4, 256, 0, stream>>>(sum2, sq2, smax, smin, gamma, c2, sref);
  softmax_p1<<<dim3(4, 64), 256, 0, stream>>>(S, sref, c2, out, esum);
  softmax_p2<<<(B_ROWS * 1024) / 256, 256, 0, stream>>>(out, esum);
}